// Round 11
// baseline (299.519 us; speedup 1.0000x reference)
//
#include <hip/hip_runtime.h>

#define NITER 10
#define CAP 96  // per-wave LDS capacity for a half edge slice

// ---------------- helpers ----------------

__device__ __forceinline__ uint32_t aload(const uint32_t* p) {
  return __hip_atomic_load(p, __ATOMIC_RELAXED, __HIP_MEMORY_SCOPE_AGENT);
}
__device__ __forceinline__ void astore(uint32_t* p, uint32_t v) {
  __hip_atomic_store(p, v, __ATOMIC_RELAXED, __HIP_MEMORY_SCOPE_AGENT);
}
__device__ __forceinline__ float bf2f_lo(uint32_t v) { return __uint_as_float(v << 16); }
__device__ __forceinline__ float bf2f_hi(uint32_t v) { return __uint_as_float(v & 0xFFFF0000u); }
__device__ __forceinline__ uint32_t f2bf_bits(float f) {  // RNE, top 16 bits
  uint32_t b = __float_as_uint(f);
  b += 0x7FFFu + ((b >> 16) & 1u);
  return b >> 16;
}
__device__ __forceinline__ uint32_t pack_bf16x2(float lo, float hi) {
  return f2bf_bits(lo) | (f2bf_bits(hi) << 16);
}

// slot barrier among gridDim.x (<=256) blocks: arrival = one sc1 store to own
// slot; detection = wave 0 polls all slots (4 sc1 loads/lane). Slots are
// monotonically increasing (targets 1,2,...), so no reset is ever needed.
// vmcnt(0) before arrival drains this wave's sc1 write-through payload stores
// to LLC; a poller seeing slot>=target therefore sees the payloads too.
__device__ __forceinline__ void gbar(uint32_t* slots, uint32_t target) {
  asm volatile("s_waitcnt vmcnt(0)" ::: "memory");
  __syncthreads();
  if (threadIdx.x < 64) {
    if (threadIdx.x == 0) astore(&slots[blockIdx.x], target);
    const int i0 = threadIdx.x * 4;
    const int nb = (int)gridDim.x;
    for (;;) {
      uint32_t v0 = aload(&slots[i0 + 0]);
      uint32_t v1 = aload(&slots[i0 + 1]);
      uint32_t v2 = aload(&slots[i0 + 2]);
      uint32_t v3 = aload(&slots[i0 + 3]);
      bool ok = (i0 + 0 >= nb || v0 >= target) && (i0 + 1 >= nb || v1 >= target) &&
                (i0 + 2 >= nb || v2 >= target) && (i0 + 3 >= nb || v3 >= target);
      if (__all(ok)) break;
      __builtin_amdgcn_s_sleep(2);
    }
  }
  __syncthreads();
  asm volatile("" ::: "memory");
}

// mini slot barrier for the 8-block setup kernel
__device__ __forceinline__ void mbar(uint32_t* ms, uint32_t target) {
  asm volatile("s_waitcnt vmcnt(0)" ::: "memory");
  __syncthreads();
  if (threadIdx.x < 64) {
    if (threadIdx.x == 0) astore(&ms[blockIdx.x], target);
    for (;;) {
      bool ok = true;
      if (threadIdx.x < 8) ok = (aload(&ms[threadIdx.x]) >= target);
      if (__all(ok)) break;
      __builtin_amdgcn_s_sleep(2);
    }
  }
  __syncthreads();
  asm volatile("" ::: "memory");
}

// ---------------- fused setup kernel (8 blocks x 1024) ----------------
// A: pruned partial histograms  B: scans (S, T, active-compaction)
// C: pruned CSR scatter         D: err zero, fx(0) publish, sensory out copy

__global__ __launch_bounds__(1024) void setup_kernel(
    const float* __restrict__ x, const int* __restrict__ src, const int* __restrict__ tgt,
    const float* __restrict__ w, const float* __restrict__ mask,
    int* __restrict__ partS, int* __restrict__ partT,
    int* __restrict__ offS, int* __restrict__ offT,
    int* __restrict__ curS, int* __restrict__ curT,
    int* __restrict__ actv, int* __restrict__ nactg,
    uint32_t* __restrict__ edgeS, uint32_t* __restrict__ edgeT,
    uint32_t* __restrict__ fx32, uint32_t* __restrict__ err32,
    float* __restrict__ out, uint32_t* __restrict__ ms, int E, int N) {
  __shared__ int h[4096];
  __shared__ int tsum[1024];
  const int bid = blockIdx.x, tid = threadIdx.x;

  // ---- A: partial histograms with mask pruning ----
  for (int i = tid; i < 2 * N; i += 1024) h[i] = 0;
  __syncthreads();
  const int chunk = E / 8;
  const int base = bid * chunk;
  const int cnt = (bid == 7) ? (E - 7 * chunk) : chunk;
  for (int k = tid; k < cnt; k += 1024) {
    int e = base + k;
    int s = src[e], t = tgt[e];
    if (mask[s] != 0.f) {          // masked-src edges contribute nothing anywhere
      atomicAdd(&h[s], 1);         // edgeS: src gathers fx[tgt]
      if (mask[t] != 0.f) atomicAdd(&h[N + t], 1);  // edgeT: only active tgt gathers
    }
  }
  __syncthreads();
  for (int i = tid; i < N; i += 1024) {
    astore((uint32_t*)&partS[bid * 2048 + i], (uint32_t)h[i]);
    astore((uint32_t*)&partT[bid * 2048 + i], (uint32_t)h[N + i]);
  }
  mbar(ms, 1);

  // ---- B: exclusive scans (block 0 -> S, 1 -> T, 2 -> active compaction) ----
  if (bid < 3) {
    int v2[2];
    int s = 0;
#pragma unroll
    for (int i2 = 0; i2 < 2; ++i2) {
      int idx = tid * 2 + i2;
      int c = 0;
      if (idx < N) {
        if (bid == 2) {
          c = (mask[idx] != 0.f) ? 1 : 0;
        } else {
          const int* part = bid ? partT : partS;
#pragma unroll
          for (int k = 0; k < 8; ++k) c += (int)aload((const uint32_t*)&part[k * 2048 + idx]);
        }
      }
      v2[i2] = s;
      s += c;
    }
    tsum[tid] = s;
    __syncthreads();
    for (int d = 1; d < 1024; d <<= 1) {
      int t = (tid >= d) ? tsum[tid - d] : 0;
      __syncthreads();
      tsum[tid] += t;
      __syncthreads();
    }
    int tbase = tsum[tid] - s;
    if (bid == 2) {
#pragma unroll
      for (int i2 = 0; i2 < 2; ++i2) {
        int idx = tid * 2 + i2;
        if (idx < N && mask[idx] != 0.f)
          astore((uint32_t*)&actv[tbase + v2[i2]], (uint32_t)idx);
      }
      if (tid == 1023) astore((uint32_t*)nactg, (uint32_t)tsum[1023]);
    } else {
      int* off = bid ? offT : offS;
      int* cur = bid ? curT : curS;
#pragma unroll
      for (int i2 = 0; i2 < 2; ++i2) {
        int idx = tid * 2 + i2;
        if (idx < N) {
          int o = tbase + v2[i2];
          astore((uint32_t*)&off[idx], (uint32_t)o);
          astore((uint32_t*)&cur[idx], (uint32_t)o);
        } else if (idx == N) {
          astore((uint32_t*)&off[idx], (uint32_t)(tbase + v2[i2]));
        }
      }
    }
  }
  mbar(ms, 2);

  // ---- C: pruned scatter into CSRs ----
  for (int k = tid; k < cnt; k += 1024) {
    int e = base + k;
    int s = src[e], t = tgt[e];
    if (mask[s] == 0.f) continue;
    uint32_t wb = __float_as_uint(w[e]);
    wb = (wb + 0x7FFFu + ((wb >> 16) & 1u)) & 0xFFFF0000u;  // bf16 bits, high half
    int p = atomicAdd(&curS[s], 1);
    astore(&edgeS[p], (uint32_t)t | wb);
    if (mask[t] != 0.f) {
      int q = atomicAdd(&curT[t], 1);
      astore(&edgeT[q], (uint32_t)s | wb);
    }
  }

  // ---- D: err32 zero, fx(0) publish, sensory out passthrough ----
  const int gs = 8 * 1024;
  const int g0 = bid * 1024 + tid;
  for (int g = g0; g < N * 64; g += gs) astore(&err32[g], 0u);
  for (int g = g0; g < N * 64; g += gs) {
    int n = g >> 6, l = g & 63;
    float x0 = x[(2 * l) * N + n];
    float x1 = x[(2 * l + 1) * N + n];
    astore(&fx32[g], pack_bf16x2(tanhf(x0), tanhf(x1)));
  }
  for (int g = g0; g < N * 128; g += gs) {
    int b = g / N, n = g - b * N;
    if (mask[n] == 0.f) out[g] = x[g];  // inactive nodes: x never changes
  }
}

// ---------------- main cooperative kernel ----------------
// 2 waves per ACTIVE node, active nodes dealt round-robin across blocks
// (p = pairslot*gridDim + bid). Messages: sc1 stores + vmcnt(0) drain at the
// slot barrier; sc1 loads (LLC). Single fx/err buffers (WAR-safe: reads and
// overwrites are separated by a barrier in both directions).

__device__ __forceinline__ void gq_lds(const uint32_t* __restrict__ se, int len,
                                       const uint32_t* buf, int lane, float& o0, float& o1) {
  float a0[8], a1[8];
#pragma unroll
  for (int j = 0; j < 8; ++j) { a0[j] = 0.f; a1[j] = 0.f; }
  for (int p = 0; p < len; p += 8) {
    uint32_t e[8];
#pragma unroll
    for (int j = 0; j < 8; ++j) e[j] = se[p + j];
    uint32_t v[8];
#pragma unroll
    for (int j = 0; j < 8; ++j) v[j] = aload(&buf[((e[j] & 0xFFFFu) << 6) + lane]);
#pragma unroll
    for (int j = 0; j < 8; ++j) {
      float wj = __uint_as_float(e[j] & 0xFFFF0000u);
      a0[j] = fmaf(wj, bf2f_lo(v[j]), a0[j]);
      a1[j] = fmaf(wj, bf2f_hi(v[j]), a1[j]);
    }
  }
  o0 = ((a0[0] + a0[1]) + (a0[2] + a0[3])) + ((a0[4] + a0[5]) + (a0[6] + a0[7]));
  o1 = ((a1[0] + a1[1]) + (a1[2] + a1[3])) + ((a1[4] + a1[5]) + (a1[6] + a1[7]));
}

__device__ __forceinline__ void gq_glb(const uint32_t* __restrict__ ed, int len,
                                       const uint32_t* buf, int lane, float& o0, float& o1) {
  float a0[8], a1[8];
#pragma unroll
  for (int j = 0; j < 8; ++j) { a0[j] = 0.f; a1[j] = 0.f; }
  for (int p = 0; p < len; p += 8) {
    uint32_t e[8], v[8];
#pragma unroll
    for (int j = 0; j < 8; ++j) {
      bool ok = (p + j) < len;
      e[j] = ok ? ed[p + j] : 0u;
      v[j] = ok ? aload(&buf[((e[j] & 0xFFFFu) << 6) + lane]) : 0u;
    }
#pragma unroll
    for (int j = 0; j < 8; ++j) {
      float wj = __uint_as_float(e[j] & 0xFFFF0000u);
      a0[j] = fmaf(wj, bf2f_lo(v[j]), a0[j]);
      a1[j] = fmaf(wj, bf2f_hi(v[j]), a1[j]);
    }
  }
  o0 = ((a0[0] + a0[1]) + (a0[2] + a0[3])) + ((a0[4] + a0[5]) + (a0[6] + a0[7]));
  o1 = ((a1[0] + a1[1]) + (a1[2] + a1[3])) + ((a1[4] + a1[5]) + (a1[6] + a1[7]));
}

__global__ __launch_bounds__(1024, 4) void pc_main(
    const float* __restrict__ x, float* __restrict__ out,
    const int* __restrict__ offS, const uint32_t* __restrict__ edS,
    const int* __restrict__ offT, const uint32_t* __restrict__ edT,
    const int* __restrict__ actv, const int* __restrict__ nactg,
    uint32_t* fx32, uint32_t* err32, const float* __restrict__ mask,
    uint32_t* slots, int N) {
  __shared__ uint32_t sE[2][16][CAP];
  __shared__ float2 psum[8][64];
  const int tid = threadIdx.x, wid = tid >> 6, lane = tid & 63;
  const int ps = wid >> 1, sub = wid & 1;
  const int nact = *nactg;  // cross-kernel: plain load is fresh at dispatch
  const int p = ps * (int)gridDim.x + (int)blockIdx.x;
  const bool act = (p < nact);
  int n = 0, i = 0, aS = 0, qlS = 0, qpS = 0, aT = 0, qlT = 0, qpT = 0;
  bool fS = true, fT = true;
  float m = 0.f, x0 = 0.f, x1 = 0.f, fx0 = 0.f, fx1 = 0.f, e0 = 0.f, e1 = 0.f;

  if (act) {
    n = actv[p];
    i = (n << 6) + lane;
    const int s0 = offS[n], degS = offS[n + 1] - s0;
    const int t0 = offT[n], degT = offT[n + 1] - t0;
    aS = s0 + ((degS * sub) >> 1); qlS = (s0 + ((degS * (sub + 1)) >> 1)) - aS;
    aT = t0 + ((degT * sub) >> 1); qlT = (t0 + ((degT * (sub + 1)) >> 1)) - aT;
    qpS = (qlS + 7) & ~7; qpT = (qlT + 7) & ~7;
    fS = (qpS <= CAP); fT = (qpT <= CAP);
    if (fS)
      for (int k = lane; k < qpS; k += 64) sE[0][wid][k] = (k < qlS) ? edS[aS + k] : 0u;
    if (fT)
      for (int k = lane; k < qpT; k += 64) sE[1][wid][k] = (k < qlT) ? edT[aT + k] : 0u;
    if (sub == 0) {
      m = mask[n];
      x0 = x[(2 * lane) * N + n];
      x1 = x[(2 * lane + 1) * N + n];
      fx0 = tanhf(x0);
      fx1 = tanhf(x1);
    }
  }
  // fx(0) was published by setup_kernel; kernel boundary is the first barrier.

  uint32_t gen = 0;
  for (int it = 0; it < NITER; ++it) {
    // phase 1: mu half-gather over fx; combine; publish err
    float p0 = 0.f, p1 = 0.f;
    if (act) {
      if (fS) gq_lds(&sE[0][wid][0], qpS, fx32, lane, p0, p1);
      else    gq_glb(edS + aS, qlS, fx32, lane, p0, p1);
      if (sub) psum[ps][lane] = make_float2(p0, p1);
    }
    __syncthreads();
    if (act && sub == 0) {
      float2 q = psum[ps][lane];
      e0 = (x0 - (p0 + q.x)) * m;
      e1 = (x1 - (p1 + q.y)) * m;
      astore(&err32[i], pack_bf16x2(e0, e1));
    }
    gbar(slots, ++gen);

    // phase 2: agg half-gather over err; combine; update x; publish fx
    if (act) {
      if (fT) gq_lds(&sE[1][wid][0], qpT, err32, lane, p0, p1);
      else    gq_glb(edT + aT, qlT, err32, lane, p0, p1);
      if (sub) psum[ps][lane] = make_float2(p0, p1);
    }
    __syncthreads();
    if (act && sub == 0) {
      float2 q = psum[ps][lane];
      const float ag0 = p0 + q.x, ag1 = p1 + q.y;
      const float dx0 = e0 - (1.f - fx0 * fx0) * ag0;
      const float dx1 = e1 - (1.f - fx1 * fx1) * ag1;
      x0 -= 0.5f * dx0 * m;
      x1 -= 0.5f * dx1 * m;
      fx0 = tanhf(x0);
      fx1 = tanhf(x1);
      if (it < NITER - 1) astore(&fx32[i], pack_bf16x2(fx0, fx1));
    }
    if (it < NITER - 1) gbar(slots, ++gen);
  }

  if (act && sub == 0) {
    out[(2 * lane) * N + n] = x0;
    out[(2 * lane + 1) * N + n] = x1;
  }
}

// ---------------- host ----------------

extern "C" void kernel_launch(void* const* d_in, const int* in_sizes, int n_in,
                              void* d_out, int out_size, void* d_ws, size_t ws_size,
                              hipStream_t stream) {
  const float* x = (const float*)d_in[0];
  const int* ei = (const int*)d_in[1];
  const float* w = (const float*)d_in[2];
  const float* mask = (const float*)d_in[3];
  int E = in_sizes[2];  // 131072
  int N = in_sizes[3];  // 2000
  const int* src = ei;
  const int* tgt = ei + E;
  float* out = (float*)d_out;

  size_t off = 0;
  auto alloc = [&](size_t bytes) -> void* {
    off = (off + 255) & ~(size_t)255;
    void* p = (char*)d_ws + off;
    off += bytes;
    return p;
  };
  uint32_t* edgeS = (uint32_t*)alloc((size_t)E * 4);
  uint32_t* edgeT = (uint32_t*)alloc((size_t)E * 4);
  int* partS = (int*)alloc(8 * 2048 * 4);
  int* partT = (int*)alloc(8 * 2048 * 4);
  int* offS = (int*)alloc(2048 * 4);
  int* offT = (int*)alloc(2048 * 4);
  int* curS = (int*)alloc(2048 * 4);
  int* curT = (int*)alloc(2048 * 4);
  int* actv = (int*)alloc(2048 * 4);
  int* nactg = (int*)alloc(64 * 4);
  uint32_t* fx32 = (uint32_t*)alloc((size_t)N * 64 * 4);
  uint32_t* err32 = (uint32_t*)alloc((size_t)N * 64 * 4);
  uint32_t* slots = (uint32_t*)alloc(256 * 4);  // main barrier slots
  uint32_t* ms = (uint32_t*)alloc(64 * 4);      // setup mini-barrier slots

  // slots+ms are contiguous; zero both (monotonic targets need a zero start)
  hipMemsetAsync(slots, 0, (256 + 64) * 4, stream);

  void* sargs[] = {(void*)&x,     (void*)&src,   (void*)&tgt,   (void*)&w,    (void*)&mask,
                   (void*)&partS, (void*)&partT, (void*)&offS,  (void*)&offT, (void*)&curS,
                   (void*)&curT,  (void*)&actv,  (void*)&nactg, (void*)&edgeS,
                   (void*)&edgeT, (void*)&fx32,  (void*)&err32, (void*)&out,  (void*)&ms,
                   (void*)&E,     (void*)&N};
  hipLaunchKernelGGL(setup_kernel, dim3(8), dim3(1024), 0, stream, x, src, tgt, w, mask, partS,
                     partT, offS, offT, curS, curT, actv, nactg, edgeS, edgeT, fx32, err32, out,
                     ms, E, N);

  const int nblk = (N + 7) / 8;  // 250 <= 256 slots, 1 block/CU
  void* args[] = {(void*)&x,    (void*)&out,   (void*)&offS,  (void*)&edgeS, (void*)&offT,
                  (void*)&edgeT, (void*)&actv, (void*)&nactg, (void*)&fx32,  (void*)&err32,
                  (void*)&mask, (void*)&slots, (void*)&N};
  hipLaunchCooperativeKernel((const void*)pc_main, dim3(nblk), dim3(1024), args, 0, stream);
}

// Round 12
// 214.069 us; speedup vs baseline: 1.3992x; 1.3992x over previous
//
#include <hip/hip_runtime.h>

#define NITER 10
#define NBLK 250   // main grid: 250 blocks x 16 waves = 8 node-pairs/block
#define CAP_H 96   // per-wave LDS capacity for a half edge slice

// ---------------- helpers ----------------

__device__ __forceinline__ uint32_t aload(const uint32_t* p) {
  return __hip_atomic_load(p, __ATOMIC_RELAXED, __HIP_MEMORY_SCOPE_AGENT);
}
__device__ __forceinline__ void astore(uint32_t* p, uint32_t v) {
  __hip_atomic_store(p, v, __ATOMIC_RELAXED, __HIP_MEMORY_SCOPE_AGENT);
}
__device__ __forceinline__ float bf2f_lo(uint32_t v) { return __uint_as_float(v << 16); }
__device__ __forceinline__ float bf2f_hi(uint32_t v) { return __uint_as_float(v & 0xFFFF0000u); }
__device__ __forceinline__ uint32_t f2bf_bits(float f) {  // RNE, top 16 bits
  uint32_t b = __float_as_uint(f);
  b += 0x7FFFu + ((b >> 16) & 1u);
  return b >> 16;
}
__device__ __forceinline__ uint32_t pack_bf16x2(float lo, float hi) {
  return f2bf_bits(lo) | (f2bf_bits(hi) << 16);
}

// ---------------- setup kernel 1: pruned partial histograms (8 blocks) ----------------
// edgeS keeps edges with mask[src]!=0 (only active src gathers mu).
// edgeT keeps edges with mask[src]!=0 AND mask[tgt]!=0 (masked src => err==0
// contributes nothing; masked tgt never gathers).

__global__ __launch_bounds__(1024) void hist_kernel(
    const int* __restrict__ src, const int* __restrict__ tgt, const float* __restrict__ mask,
    int* __restrict__ partS, int* __restrict__ partT, int E, int N) {
  __shared__ int h[4096];
  for (int i = threadIdx.x; i < 2 * N; i += 1024) h[i] = 0;
  __syncthreads();
  const int chunk = E / 8;
  const int base = blockIdx.x * chunk;
  const int cnt = (blockIdx.x == 7) ? (E - 7 * chunk) : chunk;
  for (int k = threadIdx.x; k < cnt; k += 1024) {
    int e = base + k;
    int s = src[e], t = tgt[e];
    if (mask[s] != 0.f) {
      atomicAdd(&h[s], 1);
      if (mask[t] != 0.f) atomicAdd(&h[N + t], 1);
    }
  }
  __syncthreads();
  for (int i = threadIdx.x; i < N; i += 1024) {
    partS[blockIdx.x * 2048 + i] = h[i];
    partT[blockIdx.x * 2048 + i] = h[N + i];
  }
}

// ---------------- setup kernel 2: scans (3 blocks x 256) ----------------
// block 0 -> S offsets (also zeros barrier state), 1 -> T offsets,
// 2 -> active-node compaction (actv, nactg).

__global__ void scan_kernel(const int* __restrict__ partS, const int* __restrict__ partT,
                            const float* __restrict__ mask,
                            int* __restrict__ offS, int* __restrict__ offT,
                            int* __restrict__ curS, int* __restrict__ curT,
                            int* __restrict__ actv, int* __restrict__ nactg,
                            uint32_t* __restrict__ bar, int N) {
  if (blockIdx.x == 0) {
    for (int i = threadIdx.x; i < 512; i += 256) bar[i] = 0u;  // leaves+root+gen
  }
  __shared__ int tsum[256];
  const int tid = threadIdx.x;
  const int base = tid * 8;
  int v[8];
  int s = 0;
#pragma unroll
  for (int i = 0; i < 8; ++i) {
    int idx = base + i;
    int c = 0;
    if (idx < N) {
      if (blockIdx.x == 2) {
        c = (mask[idx] != 0.f) ? 1 : 0;
      } else {
        const int* part = blockIdx.x ? partT : partS;
#pragma unroll
        for (int k = 0; k < 8; ++k) c += part[k * 2048 + idx];
      }
    }
    v[i] = s;
    s += c;
  }
  tsum[tid] = s;
  __syncthreads();
  for (int d = 1; d < 256; d <<= 1) {
    int t = (tid >= d) ? tsum[tid - d] : 0;
    __syncthreads();
    tsum[tid] += t;
    __syncthreads();
  }
  int tbase = tsum[tid] - s;
  if (blockIdx.x == 2) {
#pragma unroll
    for (int i = 0; i < 8; ++i) {
      int idx = base + i;
      if (idx < N && mask[idx] != 0.f) actv[tbase + v[i]] = idx;
    }
    if (tid == 255) *nactg = tsum[255];
  } else {
    int* off = blockIdx.x ? offT : offS;
    int* cur = blockIdx.x ? curT : curS;
#pragma unroll
    for (int i = 0; i < 8; ++i) {
      int idx = base + i;
      if (idx < N) {
        int o = tbase + v[i];
        off[idx] = o;
        cur[idx] = o;
      } else if (idx == N) {
        off[idx] = tbase + v[i];
      }
    }
  }
}

// ---------------- setup kernel 3: pruned scatter + masked-node init (512 x 256) ----------
// Also publishes fx for masked nodes (never changes) and copies their x -> out.

__global__ void scatter_kernel(const float* __restrict__ x,
                               const int* __restrict__ src, const int* __restrict__ tgt,
                               const float* __restrict__ w, const float* __restrict__ mask,
                               int* __restrict__ curS, int* __restrict__ curT,
                               uint32_t* __restrict__ edgeS, uint32_t* __restrict__ edgeT,
                               uint32_t* __restrict__ fx32, float* __restrict__ out,
                               int E, int N) {
  const int e = blockIdx.x * 256 + threadIdx.x;
  if (e < E) {
    int s = src[e], t = tgt[e];
    if (mask[s] != 0.f) {
      uint32_t wb = __float_as_uint(w[e]);
      wb = (wb + 0x7FFFu + ((wb >> 16) & 1u)) & 0xFFFF0000u;  // bf16 bits, high half
      int p = atomicAdd(&curS[s], 1);
      edgeS[p] = (uint32_t)t | wb;  // mu pass: src gathers fx[tgt]
      if (mask[t] != 0.f) {
        int q = atomicAdd(&curT[t], 1);
        edgeT[q] = (uint32_t)s | wb;  // agg pass: tgt gathers err[src]
      }
    }
  }
  const int gs = (int)gridDim.x * 256;
  for (int g = e; g < N * 64; g += gs) {
    int n = g >> 6;
    if (mask[n] == 0.f) {
      int l = g & 63;
      fx32[g] = pack_bf16x2(tanhf(x[(2 * l) * N + n]), tanhf(x[(2 * l + 1) * N + n]));
    }
  }
  for (int g = e; g < N * 128; g += gs) {
    int b = g / N, n = g - b * N;
    if (mask[n] == 0.f) out[g] = x[g];  // masked nodes: x never changes
  }
}

// ---------------- main cooperative kernel ----------------
// 2 waves per ACTIVE node, dealt round-robin (p = ps*gridDim + bid). Tree
// barrier (proven rounds 4/8/10): sc1 write-through stores + vmcnt(0) drain
// before arrival; message reads are sc1 (LLC) loads; no cache invalidation.
// Edges/actv read with plain loads: the dispatch boundary acquire makes the
// setup kernels' stores visible, and they are read-only here.

__device__ __forceinline__ void gbar(uint32_t* bar, uint32_t target) {
  asm volatile("s_waitcnt vmcnt(0)" ::: "memory");
  __syncthreads();
  if (threadIdx.x == 0) {
    const int nb = (int)gridDim.x;
    const int li = blockIdx.x & 15;
    uint32_t* leaf = bar + li * 16;
    uint32_t* root = bar + 256;
    uint32_t* gen = bar + 272;
    const int q = nb >> 4, r = nb & 15;
    const uint32_t leafsz = (uint32_t)(li < r ? q + 1 : q);
    uint32_t lo = __hip_atomic_fetch_add(leaf, 1u, __ATOMIC_RELAXED, __HIP_MEMORY_SCOPE_AGENT);
    if (lo == leafsz - 1) {
      astore(leaf, 0u);
      asm volatile("s_waitcnt vmcnt(0)" ::: "memory");
      uint32_t ro = __hip_atomic_fetch_add(root, 1u, __ATOMIC_RELAXED, __HIP_MEMORY_SCOPE_AGENT);
      if (ro == 15u) {
        astore(root, 0u);
        asm volatile("s_waitcnt vmcnt(0)" ::: "memory");
        astore(gen, target);
      }
    }
    while (aload(gen) < target) __builtin_amdgcn_s_sleep(2);
  }
  __syncthreads();
  asm volatile("" ::: "memory");
}

// half-slice gather from LDS (len multiple of 8; pad entries idx=0,w=0)
__device__ __forceinline__ void gq_lds(const uint32_t* __restrict__ se, int len,
                                       const uint32_t* buf, int lane, float& o0, float& o1) {
  float a0[8], a1[8];
#pragma unroll
  for (int j = 0; j < 8; ++j) { a0[j] = 0.f; a1[j] = 0.f; }
  for (int p = 0; p < len; p += 8) {
    uint32_t e[8];
#pragma unroll
    for (int j = 0; j < 8; ++j) e[j] = se[p + j];
    uint32_t v[8];
#pragma unroll
    for (int j = 0; j < 8; ++j) v[j] = aload(&buf[((e[j] & 0xFFFFu) << 6) + lane]);
#pragma unroll
    for (int j = 0; j < 8; ++j) {
      float wj = __uint_as_float(e[j] & 0xFFFF0000u);
      a0[j] = fmaf(wj, bf2f_lo(v[j]), a0[j]);
      a1[j] = fmaf(wj, bf2f_hi(v[j]), a1[j]);
    }
  }
  o0 = ((a0[0] + a0[1]) + (a0[2] + a0[3])) + ((a0[4] + a0[5]) + (a0[6] + a0[7]));
  o1 = ((a1[0] + a1[1]) + (a1[2] + a1[3])) + ((a1[4] + a1[5]) + (a1[6] + a1[7]));
}

// fallback: straight from global CSR, guarded (only if half-slice > CAP_H; rare)
__device__ __forceinline__ void gq_glb(const uint32_t* __restrict__ ed, int len,
                                       const uint32_t* buf, int lane, float& o0, float& o1) {
  float a0[8], a1[8];
#pragma unroll
  for (int j = 0; j < 8; ++j) { a0[j] = 0.f; a1[j] = 0.f; }
  for (int p = 0; p < len; p += 8) {
    uint32_t e[8], v[8];
#pragma unroll
    for (int j = 0; j < 8; ++j) {
      bool ok = (p + j) < len;
      e[j] = ok ? ed[p + j] : 0u;
      v[j] = ok ? aload(&buf[((e[j] & 0xFFFFu) << 6) + lane]) : 0u;
    }
#pragma unroll
    for (int j = 0; j < 8; ++j) {
      float wj = __uint_as_float(e[j] & 0xFFFF0000u);
      a0[j] = fmaf(wj, bf2f_lo(v[j]), a0[j]);
      a1[j] = fmaf(wj, bf2f_hi(v[j]), a1[j]);
    }
  }
  o0 = ((a0[0] + a0[1]) + (a0[2] + a0[3])) + ((a0[4] + a0[5]) + (a0[6] + a0[7]));
  o1 = ((a1[0] + a1[1]) + (a1[2] + a1[3])) + ((a1[4] + a1[5]) + (a1[6] + a1[7]));
}

__global__ __launch_bounds__(1024, 4) void pc_main(
    const float* __restrict__ x, float* __restrict__ out,
    const int* __restrict__ offS, const uint32_t* __restrict__ edS,
    const int* __restrict__ offT, const uint32_t* __restrict__ edT,
    const int* __restrict__ actv, const int* __restrict__ nactg,
    uint32_t* fx32, uint32_t* err32, const float* __restrict__ mask,
    uint32_t* bar, int N) {
  __shared__ uint32_t sE[2][16][CAP_H];
  __shared__ float2 psum[8][64];
  const int tid = threadIdx.x, wid = tid >> 6, lane = tid & 63;
  const int ps = wid >> 1, sub = wid & 1;
  const int nact = *nactg;
  const int p = ps * (int)gridDim.x + (int)blockIdx.x;  // round-robin deal
  const bool act = (p < nact);

  int n = 0, i = 0, aS = 0, qlS = 0, qpS = 0, aT = 0, qlT = 0, qpT = 0;
  bool fS = true, fT = true;
  float m = 0.f, x0 = 0.f, x1 = 0.f, fx0 = 0.f, fx1 = 0.f, e0 = 0.f, e1 = 0.f;

  if (act) {
    n = actv[p];
    i = (n << 6) + lane;
    const int s0 = offS[n], degS = offS[n + 1] - s0;
    const int t0 = offT[n], degT = offT[n + 1] - t0;
    aS = s0 + ((degS * sub) >> 1); qlS = (s0 + ((degS * (sub + 1)) >> 1)) - aS;
    aT = t0 + ((degT * sub) >> 1); qlT = (t0 + ((degT * (sub + 1)) >> 1)) - aT;
    qpS = (qlS + 7) & ~7; qpT = (qlT + 7) & ~7;
    fS = (qpS <= CAP_H); fT = (qpT <= CAP_H);
    if (fS)
      for (int k = lane; k < qpS; k += 64) sE[0][wid][k] = (k < qlS) ? edS[aS + k] : 0u;
    if (fT)
      for (int k = lane; k < qpT; k += 64) sE[1][wid][k] = (k < qlT) ? edT[aT + k] : 0u;
    if (sub == 0) {  // primary owns node state; lane l owns batch (2l, 2l+1)
      m = mask[n];
      x0 = x[(2 * lane) * N + n];
      x1 = x[(2 * lane + 1) * N + n];
      fx0 = tanhf(x0);
      fx1 = tanhf(x1);
      astore(&fx32[i], pack_bf16x2(fx0, fx1));
    }
  }
  uint32_t gen = 0;
  gbar(bar, ++gen);

  for (int it = 0; it < NITER; ++it) {
    // phase 1: mu half-gather over fx; combine; publish err
    float p0 = 0.f, p1 = 0.f;
    if (act) {
      if (fS) gq_lds(&sE[0][wid][0], qpS, fx32, lane, p0, p1);
      else    gq_glb(edS + aS, qlS, fx32, lane, p0, p1);
      if (sub) psum[ps][lane] = make_float2(p0, p1);
    }
    __syncthreads();
    if (act && sub == 0) {
      float2 q = psum[ps][lane];
      e0 = (x0 - (p0 + q.x)) * m;
      e1 = (x1 - (p1 + q.y)) * m;
      astore(&err32[i], pack_bf16x2(e0, e1));
    }
    gbar(bar, ++gen);

    // phase 2: agg half-gather over err; combine; update x; publish fx
    if (act) {
      if (fT) gq_lds(&sE[1][wid][0], qpT, err32, lane, p0, p1);
      else    gq_glb(edT + aT, qlT, err32, lane, p0, p1);
      if (sub) psum[ps][lane] = make_float2(p0, p1);
    }
    __syncthreads();
    if (act && sub == 0) {
      float2 q = psum[ps][lane];
      const float ag0 = p0 + q.x, ag1 = p1 + q.y;
      const float dx0 = e0 - (1.f - fx0 * fx0) * ag0;
      const float dx1 = e1 - (1.f - fx1 * fx1) * ag1;
      x0 -= 0.5f * dx0 * m;
      x1 -= 0.5f * dx1 * m;
      fx0 = tanhf(x0);
      fx1 = tanhf(x1);
      if (it < NITER - 1) astore(&fx32[i], pack_bf16x2(fx0, fx1));
    }
    if (it < NITER - 1) gbar(bar, ++gen);
  }

  if (act && sub == 0) {
    out[(2 * lane) * N + n] = x0;
    out[(2 * lane + 1) * N + n] = x1;
  }
}

// ---------------- host ----------------

extern "C" void kernel_launch(void* const* d_in, const int* in_sizes, int n_in,
                              void* d_out, int out_size, void* d_ws, size_t ws_size,
                              hipStream_t stream) {
  const float* x = (const float*)d_in[0];
  const int* ei = (const int*)d_in[1];
  const float* w = (const float*)d_in[2];
  const float* mask = (const float*)d_in[3];
  int E = in_sizes[2];  // 131072
  int N = in_sizes[3];  // 2000
  const int* src = ei;
  const int* tgt = ei + E;
  float* out = (float*)d_out;

  size_t off = 0;
  auto alloc = [&](size_t bytes) -> void* {
    off = (off + 255) & ~(size_t)255;
    void* p = (char*)d_ws + off;
    off += bytes;
    return p;
  };
  uint32_t* edgeS = (uint32_t*)alloc((size_t)E * 4);
  uint32_t* edgeT = (uint32_t*)alloc((size_t)E * 4);
  int* partS = (int*)alloc(8 * 2048 * 4);
  int* partT = (int*)alloc(8 * 2048 * 4);
  int* offS = (int*)alloc(2048 * 4);
  int* offT = (int*)alloc(2048 * 4);
  int* curS = (int*)alloc(2048 * 4);
  int* curT = (int*)alloc(2048 * 4);
  int* actv = (int*)alloc(2048 * 4);
  int* nactg = (int*)alloc(64 * 4);
  uint32_t* fx32 = (uint32_t*)alloc((size_t)N * 64 * 4);
  uint32_t* err32 = (uint32_t*)alloc((size_t)N * 64 * 4);
  uint32_t* bar = (uint32_t*)alloc(512 * 4);

  hist_kernel<<<8, 1024, 0, stream>>>(src, tgt, mask, partS, partT, E, N);
  scan_kernel<<<3, 256, 0, stream>>>(partS, partT, mask, offS, offT, curS, curT, actv, nactg,
                                     bar, N);
  scatter_kernel<<<(E + 255) / 256, 256, 0, stream>>>(x, src, tgt, w, mask, curS, curT, edgeS,
                                                      edgeT, fx32, out, E, N);

  void* args[] = {(void*)&x,     (void*)&out,   (void*)&offS,  (void*)&edgeS, (void*)&offT,
                  (void*)&edgeT, (void*)&actv,  (void*)&nactg, (void*)&fx32,  (void*)&err32,
                  (void*)&mask,  (void*)&bar,   (void*)&N};
  hipLaunchCooperativeKernel((const void*)pc_main, dim3(NBLK), dim3(1024), args, 0, stream);
}

// Round 13
// 187.020 us; speedup vs baseline: 1.6015x; 1.1446x over previous
//
#include <hip/hip_runtime.h>

#define NITER 10
#define NBLK 250   // main grid: 250 blocks (<= 256 CUs) x 16 waves, 1 block/CU
#define CAP_H 96   // per-wave LDS capacity for a half edge slice

// ---------------- helpers ----------------

__device__ __forceinline__ uint32_t aload(const uint32_t* p) {
  return __hip_atomic_load(p, __ATOMIC_RELAXED, __HIP_MEMORY_SCOPE_AGENT);
}
__device__ __forceinline__ void astore(uint32_t* p, uint32_t v) {
  __hip_atomic_store(p, v, __ATOMIC_RELAXED, __HIP_MEMORY_SCOPE_AGENT);
}
__device__ __forceinline__ float bf2f_lo(uint32_t v) { return __uint_as_float(v << 16); }
__device__ __forceinline__ float bf2f_hi(uint32_t v) { return __uint_as_float(v & 0xFFFF0000u); }
__device__ __forceinline__ uint32_t f2bf_bits(float f) {  // RNE, top 16 bits
  uint32_t b = __float_as_uint(f);
  b += 0x7FFFu + ((b >> 16) & 1u);
  return b >> 16;
}
__device__ __forceinline__ uint32_t pack_bf16x2(float lo, float hi) {
  return f2bf_bits(lo) | (f2bf_bits(hi) << 16);
}

// mini slot barrier for the 8-block setup kernel (ms zeroed by host memset)
__device__ __forceinline__ void mbar(uint32_t* ms, uint32_t target) {
  asm volatile("s_waitcnt vmcnt(0)" ::: "memory");
  __syncthreads();
  if (threadIdx.x < 64) {
    if (threadIdx.x == 0) astore(&ms[blockIdx.x], target);
    for (;;) {
      bool ok = true;
      if (threadIdx.x < 8) ok = (aload(&ms[threadIdx.x]) >= target);
      if (__all(ok)) break;
      __builtin_amdgcn_s_sleep(2);
    }
  }
  __syncthreads();
  asm volatile("" ::: "memory");
}

// ---------------- setup kernel 1: pruned hist + scans (8 blocks x 1024) ----------------
// A: partial histograms. edgeS keeps mask[src]!=0 edges; edgeT keeps
// mask[src]!=0 && mask[tgt]!=0 (masked src => err==0; masked tgt never gathers).
// B: block 0 -> S offsets, 1 -> T offsets, 2 -> active-node compaction.

__global__ __launch_bounds__(1024) void hist_scan_kernel(
    const int* __restrict__ src, const int* __restrict__ tgt, const float* __restrict__ mask,
    int* __restrict__ partS, int* __restrict__ partT,
    int* __restrict__ offS, int* __restrict__ offT,
    int* __restrict__ curS, int* __restrict__ curT,
    int* __restrict__ actv, int* __restrict__ nactg,
    uint32_t* __restrict__ ms, int E, int N) {
  __shared__ int h[4096];
  const int bid = blockIdx.x, tid = threadIdx.x;

  // ---- A ----
  for (int i = tid; i < 2 * N; i += 1024) h[i] = 0;
  __syncthreads();
  const int chunk = E / 8;
  const int base = bid * chunk;
  const int cnt = (bid == 7) ? (E - 7 * chunk) : chunk;
  for (int k = tid; k < cnt; k += 1024) {
    int e = base + k;
    int s = src[e], t = tgt[e];
    if (mask[s] != 0.f) {
      atomicAdd(&h[s], 1);
      if (mask[t] != 0.f) atomicAdd(&h[N + t], 1);
    }
  }
  __syncthreads();
  for (int i = tid; i < N; i += 1024) {
    astore((uint32_t*)&partS[bid * 2048 + i], (uint32_t)h[i]);
    astore((uint32_t*)&partT[bid * 2048 + i], (uint32_t)h[N + i]);
  }
  mbar(ms, 1);

  // ---- B ---- (reuse h[] as the scan array; 1024 threads x 2 items)
  if (bid < 3) {
    int* tsum = h;
    int v2[2];
    int s = 0;
#pragma unroll
    for (int i2 = 0; i2 < 2; ++i2) {
      int idx = tid * 2 + i2;
      int c = 0;
      if (idx < N) {
        if (bid == 2) {
          c = (mask[idx] != 0.f) ? 1 : 0;
        } else {
          const int* part = bid ? partT : partS;
#pragma unroll
          for (int k = 0; k < 8; ++k) c += (int)aload((const uint32_t*)&part[k * 2048 + idx]);
        }
      }
      v2[i2] = s;
      s += c;
    }
    __syncthreads();
    tsum[tid] = s;
    __syncthreads();
    for (int d = 1; d < 1024; d <<= 1) {
      int t = (tid >= d) ? tsum[tid - d] : 0;
      __syncthreads();
      tsum[tid] += t;
      __syncthreads();
    }
    int tbase = tsum[tid] - s;
    if (bid == 2) {
#pragma unroll
      for (int i2 = 0; i2 < 2; ++i2) {
        int idx = tid * 2 + i2;
        if (idx < N && mask[idx] != 0.f) actv[tbase + v2[i2]] = idx;
      }
      if (tid == 1023) *nactg = tsum[1023];
    } else {
      int* off = bid ? offT : offS;
      int* cur = bid ? curT : curS;
#pragma unroll
      for (int i2 = 0; i2 < 2; ++i2) {
        int idx = tid * 2 + i2;
        if (idx < N) {
          int o = tbase + v2[i2];
          off[idx] = o;
          cur[idx] = o;
        } else if (idx == N) {
          off[idx] = tbase + v2[i2];
        }
      }
    }
  }
}

// ---------------- setup kernel 2: pruned scatter + masked-node init (512 x 256) ----------

__global__ void scatter_kernel(const float* __restrict__ x,
                               const int* __restrict__ src, const int* __restrict__ tgt,
                               const float* __restrict__ w, const float* __restrict__ mask,
                               int* __restrict__ curS, int* __restrict__ curT,
                               uint32_t* __restrict__ edgeS, uint32_t* __restrict__ edgeT,
                               uint32_t* __restrict__ fx32, float* __restrict__ out,
                               int E, int N) {
  const int e = blockIdx.x * 256 + threadIdx.x;
  if (e < E) {
    int s = src[e], t = tgt[e];
    if (mask[s] != 0.f) {
      uint32_t wb = __float_as_uint(w[e]);
      wb = (wb + 0x7FFFu + ((wb >> 16) & 1u)) & 0xFFFF0000u;  // bf16 bits, high half
      int p = atomicAdd(&curS[s], 1);
      edgeS[p] = (uint32_t)t | wb;  // mu pass: src gathers fx[tgt]
      if (mask[t] != 0.f) {
        int q = atomicAdd(&curT[t], 1);
        edgeT[q] = (uint32_t)s | wb;  // agg pass: tgt gathers err[src]
      }
    }
  }
  const int gs = (int)gridDim.x * 256;
  for (int g = e; g < N * 64; g += gs) {
    int n = g >> 6;
    if (mask[n] == 0.f) {
      int l = g & 63;
      fx32[g] = pack_bf16x2(tanhf(x[(2 * l) * N + n]), tanhf(x[(2 * l + 1) * N + n]));
    }
  }
  for (int g = e; g < N * 128; g += gs) {
    int b = g / N, n = g - b * N;
    if (mask[n] == 0.f) out[g] = x[g];  // masked nodes: x never changes
  }
}

// ---------------- main persistent kernel (REGULAR launch, 1 block/CU) ----------------
// Co-residency by construction: grid 250 <= 256 CUs, launch_bounds(1024,4),
// 16KB LDS, VGPR <= 128 -> every block resident at dispatch. Tree barrier
// (proven rounds 4/8/12): sc1 write-through stores + vmcnt(0) drain before
// arrival; message reads are sc1 (LLC) loads; no cache invalidation.

__device__ __forceinline__ void gbar(uint32_t* bar, uint32_t target) {
  asm volatile("s_waitcnt vmcnt(0)" ::: "memory");
  __syncthreads();
  if (threadIdx.x == 0) {
    const int nb = (int)gridDim.x;
    const int li = blockIdx.x & 15;
    uint32_t* leaf = bar + li * 16;
    uint32_t* root = bar + 256;
    uint32_t* gen = bar + 272;
    const int q = nb >> 4, r = nb & 15;
    const uint32_t leafsz = (uint32_t)(li < r ? q + 1 : q);
    uint32_t lo = __hip_atomic_fetch_add(leaf, 1u, __ATOMIC_RELAXED, __HIP_MEMORY_SCOPE_AGENT);
    if (lo == leafsz - 1) {
      astore(leaf, 0u);
      asm volatile("s_waitcnt vmcnt(0)" ::: "memory");
      uint32_t ro = __hip_atomic_fetch_add(root, 1u, __ATOMIC_RELAXED, __HIP_MEMORY_SCOPE_AGENT);
      if (ro == 15u) {
        astore(root, 0u);
        asm volatile("s_waitcnt vmcnt(0)" ::: "memory");
        astore(gen, target);
      }
    }
    while (aload(gen) < target) __builtin_amdgcn_s_sleep(2);
  }
  __syncthreads();
  asm volatile("" ::: "memory");
}

// half-slice gather from LDS (len multiple of 8; pad entries idx=0,w=0)
__device__ __forceinline__ void gq_lds(const uint32_t* __restrict__ se, int len,
                                       const uint32_t* buf, int lane, float& o0, float& o1) {
  float a0[8], a1[8];
#pragma unroll
  for (int j = 0; j < 8; ++j) { a0[j] = 0.f; a1[j] = 0.f; }
#pragma unroll 2
  for (int p = 0; p < len; p += 8) {
    uint32_t e[8];
#pragma unroll
    for (int j = 0; j < 8; ++j) e[j] = se[p + j];
    uint32_t v[8];
#pragma unroll
    for (int j = 0; j < 8; ++j) v[j] = aload(&buf[((e[j] & 0xFFFFu) << 6) + lane]);
#pragma unroll
    for (int j = 0; j < 8; ++j) {
      float wj = __uint_as_float(e[j] & 0xFFFF0000u);
      a0[j] = fmaf(wj, bf2f_lo(v[j]), a0[j]);
      a1[j] = fmaf(wj, bf2f_hi(v[j]), a1[j]);
    }
  }
  o0 = ((a0[0] + a0[1]) + (a0[2] + a0[3])) + ((a0[4] + a0[5]) + (a0[6] + a0[7]));
  o1 = ((a1[0] + a1[1]) + (a1[2] + a1[3])) + ((a1[4] + a1[5]) + (a1[6] + a1[7]));
}

// fallback: straight from global CSR, guarded (only if half-slice > CAP_H; rare)
__device__ __forceinline__ void gq_glb(const uint32_t* __restrict__ ed, int len,
                                       const uint32_t* buf, int lane, float& o0, float& o1) {
  float a0[8], a1[8];
#pragma unroll
  for (int j = 0; j < 8; ++j) { a0[j] = 0.f; a1[j] = 0.f; }
#pragma unroll 2
  for (int p = 0; p < len; p += 8) {
    uint32_t e[8], v[8];
#pragma unroll
    for (int j = 0; j < 8; ++j) {
      bool ok = (p + j) < len;
      e[j] = ok ? ed[p + j] : 0u;
      v[j] = ok ? aload(&buf[((e[j] & 0xFFFFu) << 6) + lane]) : 0u;
    }
#pragma unroll
    for (int j = 0; j < 8; ++j) {
      float wj = __uint_as_float(e[j] & 0xFFFF0000u);
      a0[j] = fmaf(wj, bf2f_lo(v[j]), a0[j]);
      a1[j] = fmaf(wj, bf2f_hi(v[j]), a1[j]);
    }
  }
  o0 = ((a0[0] + a0[1]) + (a0[2] + a0[3])) + ((a0[4] + a0[5]) + (a0[6] + a0[7]));
  o1 = ((a1[0] + a1[1]) + (a1[2] + a1[3])) + ((a1[4] + a1[5]) + (a1[6] + a1[7]));
}

__global__ __launch_bounds__(1024, 4) void pc_main(
    const float* __restrict__ x, float* __restrict__ out,
    const int* __restrict__ offS, const uint32_t* __restrict__ edS,
    const int* __restrict__ offT, const uint32_t* __restrict__ edT,
    const int* __restrict__ actv, const int* __restrict__ nactg,
    uint32_t* fx32, uint32_t* err32, const float* __restrict__ mask,
    uint32_t* bar, int N) {
  __shared__ uint32_t sE[2][16][CAP_H];
  __shared__ float2 psum[8][64];
  const int tid = threadIdx.x, wid = tid >> 6, lane = tid & 63;
  const int ps = wid >> 1, sub = wid & 1;
  const int nact = *nactg;
  const int p = ps * (int)gridDim.x + (int)blockIdx.x;  // round-robin deal
  const bool act = (p < nact);

  int n = 0, i = 0, aS = 0, qlS = 0, qpS = 0, aT = 0, qlT = 0, qpT = 0;
  bool fS = true, fT = true;
  float m = 0.f, x0 = 0.f, x1 = 0.f, fx0 = 0.f, fx1 = 0.f, e0 = 0.f, e1 = 0.f;

  if (act) {
    n = actv[p];
    i = (n << 6) + lane;
    const int s0 = offS[n], degS = offS[n + 1] - s0;
    const int t0 = offT[n], degT = offT[n + 1] - t0;
    aS = s0 + ((degS * sub) >> 1); qlS = (s0 + ((degS * (sub + 1)) >> 1)) - aS;
    aT = t0 + ((degT * sub) >> 1); qlT = (t0 + ((degT * (sub + 1)) >> 1)) - aT;
    qpS = (qlS + 7) & ~7; qpT = (qlT + 7) & ~7;
    fS = (qpS <= CAP_H); fT = (qpT <= CAP_H);
    if (fS)
      for (int k = lane; k < qpS; k += 64) sE[0][wid][k] = (k < qlS) ? edS[aS + k] : 0u;
    if (fT)
      for (int k = lane; k < qpT; k += 64) sE[1][wid][k] = (k < qlT) ? edT[aT + k] : 0u;
    if (sub == 0) {  // primary owns node state; lane l owns batch (2l, 2l+1)
      m = mask[n];
      x0 = x[(2 * lane) * N + n];
      x1 = x[(2 * lane + 1) * N + n];
      fx0 = tanhf(x0);
      fx1 = tanhf(x1);
      astore(&fx32[i], pack_bf16x2(fx0, fx1));
    }
  }
  uint32_t gen = 0;
  gbar(bar, ++gen);

  for (int it = 0; it < NITER; ++it) {
    // phase 1: mu half-gather over fx; combine; publish err
    float p0 = 0.f, p1 = 0.f;
    if (act) {
      if (fS) gq_lds(&sE[0][wid][0], qpS, fx32, lane, p0, p1);
      else    gq_glb(edS + aS, qlS, fx32, lane, p0, p1);
      if (sub) psum[ps][lane] = make_float2(p0, p1);
    }
    __syncthreads();
    if (act && sub == 0) {
      float2 q = psum[ps][lane];
      e0 = (x0 - (p0 + q.x)) * m;
      e1 = (x1 - (p1 + q.y)) * m;
      astore(&err32[i], pack_bf16x2(e0, e1));
    }
    gbar(bar, ++gen);

    // phase 2: agg half-gather over err; combine; update x; publish fx
    if (act) {
      if (fT) gq_lds(&sE[1][wid][0], qpT, err32, lane, p0, p1);
      else    gq_glb(edT + aT, qlT, err32, lane, p0, p1);
      if (sub) psum[ps][lane] = make_float2(p0, p1);
    }
    __syncthreads();
    if (act && sub == 0) {
      float2 q = psum[ps][lane];
      const float ag0 = p0 + q.x, ag1 = p1 + q.y;
      const float dx0 = e0 - (1.f - fx0 * fx0) * ag0;
      const float dx1 = e1 - (1.f - fx1 * fx1) * ag1;
      x0 -= 0.5f * dx0 * m;
      x1 -= 0.5f * dx1 * m;
      fx0 = tanhf(x0);
      fx1 = tanhf(x1);
      if (it < NITER - 1) astore(&fx32[i], pack_bf16x2(fx0, fx1));
    }
    if (it < NITER - 1) gbar(bar, ++gen);
  }

  if (act && sub == 0) {
    out[(2 * lane) * N + n] = x0;
    out[(2 * lane + 1) * N + n] = x1;
  }
}

// ---------------- host ----------------

extern "C" void kernel_launch(void* const* d_in, const int* in_sizes, int n_in,
                              void* d_out, int out_size, void* d_ws, size_t ws_size,
                              hipStream_t stream) {
  const float* x = (const float*)d_in[0];
  const int* ei = (const int*)d_in[1];
  const float* w = (const float*)d_in[2];
  const float* mask = (const float*)d_in[3];
  int E = in_sizes[2];  // 131072
  int N = in_sizes[3];  // 2000
  const int* src = ei;
  const int* tgt = ei + E;
  float* out = (float*)d_out;

  size_t off = 0;
  auto alloc = [&](size_t bytes) -> void* {
    off = (off + 255) & ~(size_t)255;
    void* p = (char*)d_ws + off;
    off += bytes;
    return p;
  };
  uint32_t* edgeS = (uint32_t*)alloc((size_t)E * 4);
  uint32_t* edgeT = (uint32_t*)alloc((size_t)E * 4);
  int* partS = (int*)alloc(8 * 2048 * 4);
  int* partT = (int*)alloc(8 * 2048 * 4);
  int* offS = (int*)alloc(2048 * 4);
  int* offT = (int*)alloc(2048 * 4);
  int* curS = (int*)alloc(2048 * 4);
  int* curT = (int*)alloc(2048 * 4);
  int* actv = (int*)alloc(2048 * 4);
  int* nactg = (int*)alloc(64 * 4);
  uint32_t* fx32 = (uint32_t*)alloc((size_t)N * 64 * 4);
  uint32_t* err32 = (uint32_t*)alloc((size_t)N * 64 * 4);
  uint32_t* bar = (uint32_t*)alloc(512 * 4);  // tree-barrier state
  uint32_t* ms = (uint32_t*)alloc(64 * 4);    // setup mini-barrier slots (contiguous)

  // bar + ms must be zero each call (monotonic targets; ws not re-poisoned)
  hipMemsetAsync(bar, 0, (512 + 64) * 4, stream);

  hist_scan_kernel<<<8, 1024, 0, stream>>>(src, tgt, mask, partS, partT, offS, offT, curS, curT,
                                           actv, nactg, ms, E, N);
  scatter_kernel<<<(E + 255) / 256, 256, 0, stream>>>(x, src, tgt, w, mask, curS, curT, edgeS,
                                                      edgeT, fx32, out, E, N);
  // Regular launch: 250 blocks, 1 block/CU by construction -> co-resident.
  pc_main<<<NBLK, 1024, 0, stream>>>(x, out, offS, edgeS, offT, edgeT, actv, nactg, fx32, err32,
                                     mask, bar, N);
}

// Round 14
// 163.490 us; speedup vs baseline: 1.8320x; 1.1439x over previous
//
#include <hip/hip_runtime.h>

#define NITER 10
#define NBLK 250   // persistent grid: 250 blocks (<=256 CUs) x 16 waves, 1 block/CU
#define HB 32      // histogram blocks
#define CAP_H 96   // per-wave LDS capacity for a half edge slice

// ---------------- helpers ----------------

__device__ __forceinline__ uint32_t aload(const uint32_t* p) {
  return __hip_atomic_load(p, __ATOMIC_RELAXED, __HIP_MEMORY_SCOPE_AGENT);
}
__device__ __forceinline__ void astore(uint32_t* p, uint32_t v) {
  __hip_atomic_store(p, v, __ATOMIC_RELAXED, __HIP_MEMORY_SCOPE_AGENT);
}
__device__ __forceinline__ float bf2f_lo(uint32_t v) { return __uint_as_float(v << 16); }
__device__ __forceinline__ float bf2f_hi(uint32_t v) { return __uint_as_float(v & 0xFFFF0000u); }
__device__ __forceinline__ uint32_t f2bf_bits(float f) {  // RNE, top 16 bits
  uint32_t b = __float_as_uint(f);
  b += 0x7FFFu + ((b >> 16) & 1u);
  return b >> 16;
}
__device__ __forceinline__ uint32_t pack_bf16x2(float lo, float hi) {
  return f2bf_bits(lo) | (f2bf_bits(hi) << 16);
}

// ---------------- slot barrier, single sweeper ----------------
// Arrival: one sc1 store to the block's OWN slot (no RMW contention).
// Detection: block 0's wave 0 sweeps all slots (<=4 loads/lane), then stores gen;
// all other blocks poll the single gen word. Monotonic targets 1,2,... ; the
// host memset zeroes slots+gen at the start of every captured graph replay.
// vmcnt(0) before arrival drains this wave's sc1 write-through payload stores
// to LLC, so any observer that sees slot>=target also sees the payloads.
__device__ __forceinline__ void gbar(uint32_t* slots, uint32_t* gen, uint32_t target) {
  asm volatile("s_waitcnt vmcnt(0)" ::: "memory");
  __syncthreads();
  if (blockIdx.x == 0) {
    if (threadIdx.x < 64) {
      for (;;) {
        bool ok = true;
        for (int i = threadIdx.x; i < NBLK; i += 64)
          ok &= (i == 0) || (aload(&slots[i]) >= target);
        if (__all(ok)) break;
        __builtin_amdgcn_s_sleep(1);
      }
      if (threadIdx.x == 0) astore(gen, target);
    }
  } else {
    if (threadIdx.x == 0) {
      astore(&slots[blockIdx.x], target);
      while (aload(gen) < target) __builtin_amdgcn_s_sleep(2);
    }
  }
  __syncthreads();
  asm volatile("" ::: "memory");
}

// ---------------- gathers ----------------
// half-slice gather from LDS (len multiple of 8; pad entries idx=0,w=0)
__device__ __forceinline__ void gq_lds(const uint32_t* __restrict__ se, int len,
                                       const uint32_t* buf, int lane, float& o0, float& o1) {
  float a0[8], a1[8];
#pragma unroll
  for (int j = 0; j < 8; ++j) { a0[j] = 0.f; a1[j] = 0.f; }
#pragma unroll 2
  for (int p = 0; p < len; p += 8) {
    uint32_t e[8];
#pragma unroll
    for (int j = 0; j < 8; ++j) e[j] = se[p + j];
    uint32_t v[8];
#pragma unroll
    for (int j = 0; j < 8; ++j) v[j] = aload(&buf[((e[j] & 0xFFFFu) << 6) + lane]);
#pragma unroll
    for (int j = 0; j < 8; ++j) {
      float wj = __uint_as_float(e[j] & 0xFFFF0000u);
      a0[j] = fmaf(wj, bf2f_lo(v[j]), a0[j]);
      a1[j] = fmaf(wj, bf2f_hi(v[j]), a1[j]);
    }
  }
  o0 = ((a0[0] + a0[1]) + (a0[2] + a0[3])) + ((a0[4] + a0[5]) + (a0[6] + a0[7]));
  o1 = ((a1[0] + a1[1]) + (a1[2] + a1[3])) + ((a1[4] + a1[5]) + (a1[6] + a1[7]));
}

// fallback: straight from global CSR (same-kernel cross-block data -> sc1 loads)
__device__ __forceinline__ void gq_glb(const uint32_t* __restrict__ ed, int len,
                                       const uint32_t* buf, int lane, float& o0, float& o1) {
  float a0[8], a1[8];
#pragma unroll
  for (int j = 0; j < 8; ++j) { a0[j] = 0.f; a1[j] = 0.f; }
#pragma unroll 2
  for (int p = 0; p < len; p += 8) {
    uint32_t e[8], v[8];
#pragma unroll
    for (int j = 0; j < 8; ++j) {
      bool ok = (p + j) < len;
      e[j] = ok ? aload(&ed[p + j]) : 0u;
      v[j] = ok ? aload(&buf[((e[j] & 0xFFFFu) << 6) + lane]) : 0u;
    }
#pragma unroll
    for (int j = 0; j < 8; ++j) {
      float wj = __uint_as_float(e[j] & 0xFFFF0000u);
      a0[j] = fmaf(wj, bf2f_lo(v[j]), a0[j]);
      a1[j] = fmaf(wj, bf2f_hi(v[j]), a1[j]);
    }
  }
  o0 = ((a0[0] + a0[1]) + (a0[2] + a0[3])) + ((a0[4] + a0[5]) + (a0[6] + a0[7]));
  o1 = ((a1[0] + a1[1]) + (a1[2] + a1[3])) + ((a1[4] + a1[5]) + (a1[6] + a1[7]));
}

// ---------------- the single fused persistent kernel ----------------
// Phases (separated by gbar): A hist (blocks 0..31) -> B scans (blocks 0..2)
// -> C scatter + fx(0) publish + masked-node init (all blocks) -> stage + loop.
// Pruning: edgeS keeps mask[src]!=0 edges; edgeT keeps mask[src]!=0 &&
// mask[tgt]!=0. 2 waves per active node, round-robin dealt.

__global__ __launch_bounds__(1024, 4) void pc_all(
    const float* __restrict__ x, float* __restrict__ out,
    const int* __restrict__ src, const int* __restrict__ tgt,
    const float* __restrict__ w, const float* __restrict__ mask,
    int* __restrict__ partS, int* __restrict__ partT,
    int* __restrict__ offS, int* __restrict__ offT,
    int* __restrict__ curS, int* __restrict__ curT,
    int* __restrict__ actv, int* __restrict__ nactg,
    uint32_t* __restrict__ edgeS, uint32_t* __restrict__ edgeT,
    uint32_t* fx32, uint32_t* err32, uint32_t* barbuf, int E, int N) {
  __shared__ int h[4096];                 // 16 KB: hist + scan tsum (reused)
  __shared__ uint32_t sE[2][16][CAP_H];   // 12 KB: per-wave edge slices
  __shared__ float2 psum[8][64];          // 4 KB: pair partial sums
  uint32_t* slots = barbuf;
  uint32_t* gen = barbuf + 288;  // separate cache line from slots[0..255]

  const int bid = blockIdx.x, tid = threadIdx.x;
  const int wid = tid >> 6, lane = tid & 63;

  // ---- A: pruned partial histograms ----
  if (bid < HB) {
    for (int i = tid; i < 2 * N; i += 1024) h[i] = 0;
    __syncthreads();
    const int chunk = (E + HB - 1) / HB;
    const int base = bid * chunk;
    const int end = min(base + chunk, E);
    for (int e = base + tid; e < end; e += 1024) {
      int s = src[e], t = tgt[e];
      if (mask[s] != 0.f) {
        atomicAdd(&h[s], 1);
        if (mask[t] != 0.f) atomicAdd(&h[N + t], 1);
      }
    }
    __syncthreads();
    for (int i = tid; i < N; i += 1024) {
      astore((uint32_t*)&partS[bid * 2048 + i], (uint32_t)h[i]);
      astore((uint32_t*)&partT[bid * 2048 + i], (uint32_t)h[N + i]);
    }
  }
  gbar(slots, gen, 1);

  // ---- B: exclusive scans (block 0 -> S, 1 -> T, 2 -> active compaction) ----
  if (bid < 3) {
    int* tsum = h;
    int v2[2];
    int s = 0;
#pragma unroll
    for (int i2 = 0; i2 < 2; ++i2) {
      int idx = tid * 2 + i2;
      int c = 0;
      if (idx < N) {
        if (bid == 2) {
          c = (mask[idx] != 0.f) ? 1 : 0;
        } else {
          const uint32_t* part = (const uint32_t*)(bid ? partT : partS);
          for (int k = 0; k < HB; ++k) c += (int)aload(&part[k * 2048 + idx]);
        }
      }
      v2[i2] = s;
      s += c;
    }
    __syncthreads();
    tsum[tid] = s;
    __syncthreads();
    for (int d = 1; d < 1024; d <<= 1) {
      int t = (tid >= d) ? tsum[tid - d] : 0;
      __syncthreads();
      tsum[tid] += t;
      __syncthreads();
    }
    int tbase = tsum[tid] - s;
    if (bid == 2) {
#pragma unroll
      for (int i2 = 0; i2 < 2; ++i2) {
        int idx = tid * 2 + i2;
        if (idx < N && mask[idx] != 0.f)
          astore((uint32_t*)&actv[tbase + v2[i2]], (uint32_t)idx);
      }
      if (tid == 1023) astore((uint32_t*)nactg, (uint32_t)tsum[1023]);
    } else {
      int* off = bid ? offT : offS;
      int* cur = bid ? curT : curS;
#pragma unroll
      for (int i2 = 0; i2 < 2; ++i2) {
        int idx = tid * 2 + i2;
        if (idx < N) {
          int o = tbase + v2[i2];
          astore((uint32_t*)&off[idx], (uint32_t)o);
          astore((uint32_t*)&cur[idx], (uint32_t)o);
        } else if (idx == N) {
          astore((uint32_t*)&off[idx], (uint32_t)(tbase + v2[i2]));
        }
      }
    }
  }
  gbar(slots, gen, 2);

  // ---- C: pruned scatter (all blocks) + active setup + fx(0) + masked init ----
  {
    const int chunk = (E + NBLK - 1) / NBLK;
    const int base = bid * chunk;
    const int end = min(base + chunk, E);
    for (int e = base + tid; e < end; e += 1024) {
      int s = src[e], t = tgt[e];
      if (mask[s] != 0.f) {
        uint32_t wb = __float_as_uint(w[e]);
        wb = (wb + 0x7FFFu + ((wb >> 16) & 1u)) & 0xFFFF0000u;  // bf16 bits, high half
        int p = atomicAdd(&curS[s], 1);
        astore(&edgeS[p], (uint32_t)t | wb);  // mu pass: src gathers fx[tgt]
        if (mask[t] != 0.f) {
          int q = atomicAdd(&curT[t], 1);
          astore(&edgeT[q], (uint32_t)s | wb);  // agg pass: tgt gathers err[src]
        }
      }
    }
  }

  const int ps = wid >> 1, sub = wid & 1;
  const int nact = (int)aload((const uint32_t*)nactg);
  const int p = ps * NBLK + bid;  // round-robin deal
  const bool act = (p < nact);
  int n = 0, i = 0, aS = 0, qlS = 0, qpS = 0, aT = 0, qlT = 0, qpT = 0;
  bool fS = true, fT = true;
  float m = 0.f, x0 = 0.f, x1 = 0.f, fx0 = 0.f, fx1 = 0.f, e0 = 0.f, e1 = 0.f;

  if (act) {
    n = (int)aload((const uint32_t*)&actv[p]);
    i = (n << 6) + lane;
    const uint32_t* offSu = (const uint32_t*)offS;
    const uint32_t* offTu = (const uint32_t*)offT;
    const int s0 = (int)aload(&offSu[n]), degS = (int)aload(&offSu[n + 1]) - s0;
    const int t0 = (int)aload(&offTu[n]), degT = (int)aload(&offTu[n + 1]) - t0;
    aS = s0 + ((degS * sub) >> 1); qlS = (s0 + ((degS * (sub + 1)) >> 1)) - aS;
    aT = t0 + ((degT * sub) >> 1); qlT = (t0 + ((degT * (sub + 1)) >> 1)) - aT;
    qpS = (qlS + 7) & ~7; qpT = (qlT + 7) & ~7;
    fS = (qpS <= CAP_H); fT = (qpT <= CAP_H);
    if (sub == 0) {  // primary owns node state; lane l owns batch (2l, 2l+1)
      m = mask[n];
      x0 = x[(2 * lane) * N + n];
      x1 = x[(2 * lane + 1) * N + n];
      fx0 = tanhf(x0);
      fx1 = tanhf(x1);
      astore(&fx32[i], pack_bf16x2(fx0, fx1));
    }
  }
  // masked nodes: publish constant fx once; x never changes -> out = x
  for (int g = bid * 1024 + tid; g < N * 64; g += NBLK * 1024) {
    int nn = g >> 6;
    if (mask[nn] == 0.f) {
      int l = g & 63;
      astore(&fx32[g], pack_bf16x2(tanhf(x[(2 * l) * N + nn]), tanhf(x[(2 * l + 1) * N + nn])));
    }
  }
  for (int g = bid * 1024 + tid; g < N * 128; g += NBLK * 1024) {
    int b = g / N, nn = g - b * N;
    if (mask[nn] == 0.f) out[g] = x[g];
  }
  gbar(slots, gen, 3);

  // ---- stage this wave's half-slices into LDS (wave-private; edges via sc1) ----
  if (act) {
    if (fS)
      for (int k = lane; k < qpS; k += 64) sE[0][wid][k] = (k < qlS) ? aload(&edgeS[aS + k]) : 0u;
    if (fT)
      for (int k = lane; k < qpT; k += 64) sE[1][wid][k] = (k < qlT) ? aload(&edgeT[aT + k]) : 0u;
  }

  // ---- main loop ----
  uint32_t g = 3;
  for (int it = 0; it < NITER; ++it) {
    // phase 1: mu half-gather over fx; combine; publish err
    float p0 = 0.f, p1 = 0.f;
    if (act) {
      if (fS) gq_lds(&sE[0][wid][0], qpS, fx32, lane, p0, p1);
      else    gq_glb(edgeS + aS, qlS, fx32, lane, p0, p1);
      if (sub) psum[ps][lane] = make_float2(p0, p1);
    }
    __syncthreads();
    if (act && sub == 0) {
      float2 q = psum[ps][lane];
      e0 = (x0 - (p0 + q.x)) * m;
      e1 = (x1 - (p1 + q.y)) * m;
      astore(&err32[i], pack_bf16x2(e0, e1));
    }
    gbar(slots, gen, ++g);

    // phase 2: agg half-gather over err; combine; update x; publish fx
    if (act) {
      if (fT) gq_lds(&sE[1][wid][0], qpT, err32, lane, p0, p1);
      else    gq_glb(edgeT + aT, qlT, err32, lane, p0, p1);
      if (sub) psum[ps][lane] = make_float2(p0, p1);
    }
    __syncthreads();
    if (act && sub == 0) {
      float2 q = psum[ps][lane];
      const float ag0 = p0 + q.x, ag1 = p1 + q.y;
      const float dx0 = e0 - (1.f - fx0 * fx0) * ag0;
      const float dx1 = e1 - (1.f - fx1 * fx1) * ag1;
      x0 -= 0.5f * dx0 * m;
      x1 -= 0.5f * dx1 * m;
      fx0 = tanhf(x0);
      fx1 = tanhf(x1);
      if (it < NITER - 1) astore(&fx32[i], pack_bf16x2(fx0, fx1));
    }
    if (it < NITER - 1) gbar(slots, gen, ++g);
  }

  if (act && sub == 0) {
    out[(2 * lane) * N + n] = x0;
    out[(2 * lane + 1) * N + n] = x1;
  }
}

// ---------------- host ----------------

extern "C" void kernel_launch(void* const* d_in, const int* in_sizes, int n_in,
                              void* d_out, int out_size, void* d_ws, size_t ws_size,
                              hipStream_t stream) {
  const float* x = (const float*)d_in[0];
  const int* ei = (const int*)d_in[1];
  const float* w = (const float*)d_in[2];
  const float* mask = (const float*)d_in[3];
  int E = in_sizes[2];  // 131072
  int N = in_sizes[3];  // 2000
  const int* src = ei;
  const int* tgt = ei + E;
  float* out = (float*)d_out;

  size_t off = 0;
  auto alloc = [&](size_t bytes) -> void* {
    off = (off + 255) & ~(size_t)255;
    void* p = (char*)d_ws + off;
    off += bytes;
    return p;
  };
  uint32_t* edgeS = (uint32_t*)alloc((size_t)E * 4);
  uint32_t* edgeT = (uint32_t*)alloc((size_t)E * 4);
  int* partS = (int*)alloc((size_t)HB * 2048 * 4);
  int* partT = (int*)alloc((size_t)HB * 2048 * 4);
  int* offS = (int*)alloc(2048 * 4);
  int* offT = (int*)alloc(2048 * 4);
  int* curS = (int*)alloc(2048 * 4);
  int* curT = (int*)alloc(2048 * 4);
  int* actv = (int*)alloc(2048 * 4);
  int* nactg = (int*)alloc(64 * 4);
  uint32_t* fx32 = (uint32_t*)alloc((size_t)N * 64 * 4);
  uint32_t* err32 = (uint32_t*)alloc((size_t)N * 64 * 4);
  uint32_t* barbuf = (uint32_t*)alloc(512 * 4);  // slots[256] + gen

  // barrier state must be zero at the start of every replay (monotonic targets)
  hipMemsetAsync(barbuf, 0, 512 * 4, stream);

  pc_all<<<NBLK, 1024, 0, stream>>>(x, out, src, tgt, w, mask, partS, partT, offS, offT,
                                    curS, curT, actv, nactg, edgeS, edgeT, fx32, err32,
                                    barbuf, E, N);
}

// Round 15
// 160.778 us; speedup vs baseline: 1.8629x; 1.0169x over previous
//
#include <hip/hip_runtime.h>

#define NITER 10
#define NBLK 250   // persistent grid: 250 blocks (<=256 CUs) x 16 waves, 1 block/CU
#define HB 32      // histogram blocks
#define CAP_H 96   // per-wave LDS capacity for a half edge slice

// ---------------- helpers ----------------

__device__ __forceinline__ uint32_t aload(const uint32_t* p) {
  return __hip_atomic_load(p, __ATOMIC_RELAXED, __HIP_MEMORY_SCOPE_AGENT);
}
__device__ __forceinline__ void astore(uint32_t* p, uint32_t v) {
  __hip_atomic_store(p, v, __ATOMIC_RELAXED, __HIP_MEMORY_SCOPE_AGENT);
}
__device__ __forceinline__ float bf2f_lo(uint32_t v) { return __uint_as_float(v << 16); }
__device__ __forceinline__ float bf2f_hi(uint32_t v) { return __uint_as_float(v & 0xFFFF0000u); }
__device__ __forceinline__ uint32_t f2bf_bits(float f) {  // RNE, top 16 bits
  uint32_t b = __float_as_uint(f);
  b += 0x7FFFu + ((b >> 16) & 1u);
  return b >> 16;
}
__device__ __forceinline__ uint32_t pack_bf16x2(float lo, float hi) {
  return f2bf_bits(lo) | (f2bf_bits(hi) << 16);
}

// ---------------- slot barrier, single sweeper (round-14 proven) ----------------
__device__ __forceinline__ void gbar(uint32_t* slots, uint32_t* gen, uint32_t target) {
  asm volatile("s_waitcnt vmcnt(0)" ::: "memory");
  __syncthreads();
  if (blockIdx.x == 0) {
    if (threadIdx.x < 64) {
      for (;;) {
        bool ok = true;
        for (int i = threadIdx.x; i < NBLK; i += 64)
          ok &= (i == 0) || (aload(&slots[i]) >= target);
        if (__all(ok)) break;
        __builtin_amdgcn_s_sleep(1);
      }
      if (threadIdx.x == 0) astore(gen, target);
    }
  } else {
    if (threadIdx.x == 0) {
      astore(&slots[blockIdx.x], target);
      while (aload(gen) < target) __builtin_amdgcn_s_sleep(2);
    }
  }
  __syncthreads();
  asm volatile("" ::: "memory");
}

// ---------------- gathers ----------------
// L2M=true: plain loads (L2-cacheable; safe because each message buffer is
// written once per launch, read only after the barrier, and values are
// replay-invariant; dispatch boundary invalidates L2 - proven rounds 1-3).
// L2M=false: sc1 loads (LLC), single-buffer fallback (round-14 proven).

template <bool L2M>
__device__ __forceinline__ uint32_t mload(const uint32_t* p) {
  if constexpr (L2M) return *p;
  else return aload(p);
}

template <bool L2M>
__device__ __forceinline__ void gq_lds(const uint32_t* __restrict__ se, int len,
                                       const uint32_t* buf, int lane, float& o0, float& o1) {
  float a0[8], a1[8];
#pragma unroll
  for (int j = 0; j < 8; ++j) { a0[j] = 0.f; a1[j] = 0.f; }
#pragma unroll 2
  for (int p = 0; p < len; p += 8) {
    uint32_t e[8];
#pragma unroll
    for (int j = 0; j < 8; ++j) e[j] = se[p + j];
    uint32_t v[8];
#pragma unroll
    for (int j = 0; j < 8; ++j) v[j] = mload<L2M>(&buf[((e[j] & 0xFFFFu) << 6) + lane]);
#pragma unroll
    for (int j = 0; j < 8; ++j) {
      float wj = __uint_as_float(e[j] & 0xFFFF0000u);
      a0[j] = fmaf(wj, bf2f_lo(v[j]), a0[j]);
      a1[j] = fmaf(wj, bf2f_hi(v[j]), a1[j]);
    }
  }
  o0 = ((a0[0] + a0[1]) + (a0[2] + a0[3])) + ((a0[4] + a0[5]) + (a0[6] + a0[7]));
  o1 = ((a1[0] + a1[1]) + (a1[2] + a1[3])) + ((a1[4] + a1[5]) + (a1[6] + a1[7]));
}

template <bool L2M>
__device__ __forceinline__ void gq_glb(const uint32_t* __restrict__ ed, int len,
                                       const uint32_t* buf, int lane, float& o0, float& o1) {
  float a0[8], a1[8];
#pragma unroll
  for (int j = 0; j < 8; ++j) { a0[j] = 0.f; a1[j] = 0.f; }
#pragma unroll 2
  for (int p = 0; p < len; p += 8) {
    uint32_t e[8], v[8];
#pragma unroll
    for (int j = 0; j < 8; ++j) {
      bool ok = (p + j) < len;
      e[j] = ok ? aload(&ed[p + j]) : 0u;
      v[j] = ok ? mload<L2M>(&buf[((e[j] & 0xFFFFu) << 6) + lane]) : 0u;
    }
#pragma unroll
    for (int j = 0; j < 8; ++j) {
      float wj = __uint_as_float(e[j] & 0xFFFF0000u);
      a0[j] = fmaf(wj, bf2f_lo(v[j]), a0[j]);
      a1[j] = fmaf(wj, bf2f_hi(v[j]), a1[j]);
    }
  }
  o0 = ((a0[0] + a0[1]) + (a0[2] + a0[3])) + ((a0[4] + a0[5]) + (a0[6] + a0[7]));
  o1 = ((a1[0] + a1[1]) + (a1[2] + a1[3])) + ((a1[4] + a1[5]) + (a1[6] + a1[7]));
}

// ---------------- the single fused persistent kernel ----------------
// Phases (gbar-separated): A hist -> B scans -> C scatter + inits -> loop.
// L2M: fx/err rotate through NITER buffers (stride fstr/estr words per iter);
// publishes sc1, gathers plain. Fallback: fstr=estr=0, sc1 gathers.

template <bool L2M>
__global__ __launch_bounds__(1024, 4) void pc_all(
    const float* __restrict__ x, float* __restrict__ out,
    const int* __restrict__ src, const int* __restrict__ tgt,
    const float* __restrict__ w, const float* __restrict__ mask,
    int* __restrict__ partS, int* __restrict__ partT,
    int* __restrict__ offS, int* __restrict__ offT,
    int* __restrict__ curS, int* __restrict__ curT,
    int* __restrict__ actv, int* __restrict__ nactg,
    uint32_t* __restrict__ edgeS, uint32_t* __restrict__ edgeT,
    uint32_t* fx32, uint32_t* err32, uint32_t* barbuf, int E, int N) {
  __shared__ int h[4096];
  __shared__ uint32_t sE[2][16][CAP_H];
  __shared__ float2 psum[8][64];
  uint32_t* slots = barbuf;
  uint32_t* gen = barbuf + 288;

  const int bid = blockIdx.x, tid = threadIdx.x;
  const int wid = tid >> 6, lane = tid & 63;
  const int row = N * 64;                 // words per message buffer
  const int fstr = L2M ? row : 0;         // per-iteration buffer stride
  const int estr = L2M ? row : 0;

  // ---- A: pruned partial histograms ----
  if (bid < HB) {
    for (int i = tid; i < 2 * N; i += 1024) h[i] = 0;
    __syncthreads();
    const int chunk = (E + HB - 1) / HB;
    const int base = bid * chunk;
    const int end = min(base + chunk, E);
    for (int e = base + tid; e < end; e += 1024) {
      int s = src[e], t = tgt[e];
      if (mask[s] != 0.f) {
        atomicAdd(&h[s], 1);
        if (mask[t] != 0.f) atomicAdd(&h[N + t], 1);
      }
    }
    __syncthreads();
    for (int i = tid; i < N; i += 1024) {
      astore((uint32_t*)&partS[bid * 2048 + i], (uint32_t)h[i]);
      astore((uint32_t*)&partT[bid * 2048 + i], (uint32_t)h[N + i]);
    }
  }
  gbar(slots, gen, 1);

  // ---- B: exclusive scans (block 0 -> S, 1 -> T, 2 -> active compaction) ----
  if (bid < 3) {
    int* tsum = h;
    int v2[2];
    int s = 0;
#pragma unroll
    for (int i2 = 0; i2 < 2; ++i2) {
      int idx = tid * 2 + i2;
      int c = 0;
      if (idx < N) {
        if (bid == 2) {
          c = (mask[idx] != 0.f) ? 1 : 0;
        } else {
          const uint32_t* part = (const uint32_t*)(bid ? partT : partS);
          for (int k = 0; k < HB; ++k) c += (int)aload(&part[k * 2048 + idx]);
        }
      }
      v2[i2] = s;
      s += c;
    }
    __syncthreads();
    tsum[tid] = s;
    __syncthreads();
    for (int d = 1; d < 1024; d <<= 1) {
      int t = (tid >= d) ? tsum[tid - d] : 0;
      __syncthreads();
      tsum[tid] += t;
      __syncthreads();
    }
    int tbase = tsum[tid] - s;
    if (bid == 2) {
#pragma unroll
      for (int i2 = 0; i2 < 2; ++i2) {
        int idx = tid * 2 + i2;
        if (idx < N && mask[idx] != 0.f)
          astore((uint32_t*)&actv[tbase + v2[i2]], (uint32_t)idx);
      }
      if (tid == 1023) astore((uint32_t*)nactg, (uint32_t)tsum[1023]);
    } else {
      int* off = bid ? offT : offS;
      int* cur = bid ? curT : curS;
#pragma unroll
      for (int i2 = 0; i2 < 2; ++i2) {
        int idx = tid * 2 + i2;
        if (idx < N) {
          int o = tbase + v2[i2];
          astore((uint32_t*)&off[idx], (uint32_t)o);
          astore((uint32_t*)&cur[idx], (uint32_t)o);
        } else if (idx == N) {
          astore((uint32_t*)&off[idx], (uint32_t)(tbase + v2[i2]));
        }
      }
    }
  }
  gbar(slots, gen, 2);

  // ---- C: pruned scatter + active setup + fx(0) + masked init ----
  {
    const int chunk = (E + NBLK - 1) / NBLK;
    const int base = bid * chunk;
    const int end = min(base + chunk, E);
    for (int e = base + tid; e < end; e += 1024) {
      int s = src[e], t = tgt[e];
      if (mask[s] != 0.f) {
        uint32_t wb = __float_as_uint(w[e]);
        wb = (wb + 0x7FFFu + ((wb >> 16) & 1u)) & 0xFFFF0000u;  // bf16 bits, high half
        int p = atomicAdd(&curS[s], 1);
        astore(&edgeS[p], (uint32_t)t | wb);  // mu pass: src gathers fx[tgt]
        if (mask[t] != 0.f) {
          int q = atomicAdd(&curT[t], 1);
          astore(&edgeT[q], (uint32_t)s | wb);  // agg pass: tgt gathers err[src]
        }
      }
    }
  }

  const int ps = wid >> 1, sub = wid & 1;
  const int nact = (int)aload((const uint32_t*)nactg);
  const int p = ps * NBLK + bid;
  const bool act = (p < nact);
  int n = 0, i = 0, aS = 0, qlS = 0, qpS = 0, aT = 0, qlT = 0, qpT = 0;
  bool fS = true, fT = true;
  float m = 0.f, x0 = 0.f, x1 = 0.f, fx0 = 0.f, fx1 = 0.f, e0 = 0.f, e1 = 0.f;

  if (act) {
    n = (int)aload((const uint32_t*)&actv[p]);
    i = (n << 6) + lane;
    const uint32_t* offSu = (const uint32_t*)offS;
    const uint32_t* offTu = (const uint32_t*)offT;
    const int s0 = (int)aload(&offSu[n]), degS = (int)aload(&offSu[n + 1]) - s0;
    const int t0 = (int)aload(&offTu[n]), degT = (int)aload(&offTu[n + 1]) - t0;
    aS = s0 + ((degS * sub) >> 1); qlS = (s0 + ((degS * (sub + 1)) >> 1)) - aS;
    aT = t0 + ((degT * sub) >> 1); qlT = (t0 + ((degT * (sub + 1)) >> 1)) - aT;
    qpS = (qlS + 7) & ~7; qpT = (qlT + 7) & ~7;
    fS = (qpS <= CAP_H); fT = (qpT <= CAP_H);
    if (sub == 0) {  // primary owns node state; lane l owns batch (2l, 2l+1)
      m = mask[n];
      x0 = x[(2 * lane) * N + n];
      x1 = x[(2 * lane + 1) * N + n];
      fx0 = tanhf(x0);
      fx1 = tanhf(x1);
      astore(&fx32[i], pack_bf16x2(fx0, fx1));  // F_0
    }
  }
  // masked nodes: constant fx -> every F_k buffer; x never changes -> out = x
  for (int g = bid * 1024 + tid; g < row; g += NBLK * 1024) {
    int nn = g >> 6;
    if (mask[nn] == 0.f) {
      int l = g & 63;
      uint32_t pv = pack_bf16x2(tanhf(x[(2 * l) * N + nn]), tanhf(x[(2 * l + 1) * N + nn]));
      if constexpr (L2M) {
        for (int k = 0; k < NITER; ++k) astore(&fx32[(size_t)k * row + g], pv);
      } else {
        astore(&fx32[g], pv);
      }
    }
  }
  for (int g = bid * 1024 + tid; g < N * 128; g += NBLK * 1024) {
    int b = g / N, nn = g - b * N;
    if (mask[nn] == 0.f) out[g] = x[g];
  }
  gbar(slots, gen, 3);

  // ---- stage this wave's half-slices into LDS (wave-private) ----
  if (act) {
    if (fS)
      for (int k = lane; k < qpS; k += 64) sE[0][wid][k] = (k < qlS) ? aload(&edgeS[aS + k]) : 0u;
    if (fT)
      for (int k = lane; k < qpT; k += 64) sE[1][wid][k] = (k < qlT) ? aload(&edgeT[aT + k]) : 0u;
  }

  // ---- main loop ----
  uint32_t g = 3;
  for (int it = 0; it < NITER; ++it) {
    const uint32_t* Fk = fx32 + (size_t)it * fstr;   // read buffer for this iter
    uint32_t* Ek = err32 + (size_t)it * estr;
    // phase 1: mu half-gather over F_it; combine; publish E_it
    float p0 = 0.f, p1 = 0.f;
    if (act) {
      if (fS) gq_lds<L2M>(&sE[0][wid][0], qpS, Fk, lane, p0, p1);
      else    gq_glb<L2M>(edgeS + aS, qlS, Fk, lane, p0, p1);
      if (sub) psum[ps][lane] = make_float2(p0, p1);
    }
    __syncthreads();
    if (act && sub == 0) {
      float2 q = psum[ps][lane];
      e0 = (x0 - (p0 + q.x)) * m;
      e1 = (x1 - (p1 + q.y)) * m;
      astore(&Ek[i], pack_bf16x2(e0, e1));
    }
    gbar(slots, gen, ++g);

    // phase 2: agg half-gather over E_it; combine; update x; publish F_{it+1}
    if (act) {
      if (fT) gq_lds<L2M>(&sE[1][wid][0], qpT, Ek, lane, p0, p1);
      else    gq_glb<L2M>(edgeT + aT, qlT, Ek, lane, p0, p1);
      if (sub) psum[ps][lane] = make_float2(p0, p1);
    }
    __syncthreads();
    if (act && sub == 0) {
      float2 q = psum[ps][lane];
      const float ag0 = p0 + q.x, ag1 = p1 + q.y;
      const float dx0 = e0 - (1.f - fx0 * fx0) * ag0;
      const float dx1 = e1 - (1.f - fx1 * fx1) * ag1;
      x0 -= 0.5f * dx0 * m;
      x1 -= 0.5f * dx1 * m;
      fx0 = tanhf(x0);
      fx1 = tanhf(x1);
      if (it < NITER - 1) astore(&fx32[(size_t)(it + 1) * fstr + i], pack_bf16x2(fx0, fx1));
    }
    if (it < NITER - 1) gbar(slots, gen, ++g);
  }

  if (act && sub == 0) {
    out[(2 * lane) * N + n] = x0;
    out[(2 * lane + 1) * N + n] = x1;
  }
}

// ---------------- host ----------------

extern "C" void kernel_launch(void* const* d_in, const int* in_sizes, int n_in,
                              void* d_out, int out_size, void* d_ws, size_t ws_size,
                              hipStream_t stream) {
  const float* x = (const float*)d_in[0];
  const int* ei = (const int*)d_in[1];
  const float* w = (const float*)d_in[2];
  const float* mask = (const float*)d_in[3];
  int E = in_sizes[2];  // 131072
  int N = in_sizes[3];  // 2000
  const int* src = ei;
  const int* tgt = ei + E;
  float* out = (float*)d_out;

  size_t off = 0;
  auto alloc = [&](size_t bytes) -> void* {
    off = (off + 255) & ~(size_t)255;
    void* p = (char*)d_ws + off;
    off += bytes;
    return p;
  };
  uint32_t* edgeS = (uint32_t*)alloc((size_t)E * 4);
  uint32_t* edgeT = (uint32_t*)alloc((size_t)E * 4);
  int* partS = (int*)alloc((size_t)HB * 2048 * 4);
  int* partT = (int*)alloc((size_t)HB * 2048 * 4);
  int* offS = (int*)alloc(2048 * 4);
  int* offT = (int*)alloc(2048 * 4);
  int* curS = (int*)alloc(2048 * 4);
  int* curT = (int*)alloc(2048 * 4);
  int* actv = (int*)alloc(2048 * 4);
  int* nactg = (int*)alloc(64 * 4);
  uint32_t* barbuf = (uint32_t*)alloc(512 * 4);

  const size_t row = (size_t)N * 64 * 4;  // bytes per message buffer
  // try NITER rotating buffers for fx and err (L2-cacheable gathers)
  bool l2mode = (off + 2 * (size_t)NITER * row + 512) <= ws_size;
  uint32_t* fx32, *err32;
  if (l2mode) {
    fx32 = (uint32_t*)alloc((size_t)NITER * row);
    err32 = (uint32_t*)alloc((size_t)NITER * row);
  } else {
    fx32 = (uint32_t*)alloc(row);
    err32 = (uint32_t*)alloc(row);
  }

  // barrier state must be zero at the start of every replay (monotonic targets)
  hipMemsetAsync(barbuf, 0, 512 * 4, stream);

  if (l2mode) {
    pc_all<true><<<NBLK, 1024, 0, stream>>>(x, out, src, tgt, w, mask, partS, partT, offS, offT,
                                            curS, curT, actv, nactg, edgeS, edgeT, fx32, err32,
                                            barbuf, E, N);
  } else {
    pc_all<false><<<NBLK, 1024, 0, stream>>>(x, out, src, tgt, w, mask, partS, partT, offS, offT,
                                             curS, curT, actv, nactg, edgeS, edgeT, fx32, err32,
                                             barbuf, E, N);
  }
}